// Round 5
// baseline (1171.263 us; speedup 1.0000x reference)
//
#include <hip/hip_runtime.h>
#include <math.h>

// SSIM via fully separable pipeline, software-pipelined staging version,
// consolidated. img1,img2: [32,3,512,512] fp32 -> scalar mean.
//
// Round-7: conservative consolidation. Rounds 4-6 showed:
//  - 4-LDS-plane u/v: 128-VGPR allocator ceiling -> acc ring to scratch
//    (WRITE 5GB, 18x slower), regardless of index constness.
//  - 2-LDS-plane u/v (round 6): no spill (80 VGPR) but SLOWER than the
//    round-3 baseline (238 vs 181us, VALUBusy 84->70%) -- busy time went UP
//    despite fewer static ops. The u/v staged-plane form does not carry its
//    weight; reverted.
// This round = round-3 kernel VERBATIM (proven 181us / 84 VGPR / 84% busy)
// plus exactly two strictly-shrinking changes:
//  1. hxx,hyy merged into hss = conv(x^2+y^2): emit only needs
//     sigma1^2+sigma2^2 = mss - (mu1^2+mu2^2). h-conv stays 7 ops/tap,
//     ring drops 55->44 fmas, register demand strictly decreases.
//  2. IEEE divide -> v_rcp + 1 Newton step (absmax stayed 0.0 with this in
//     rounds 4/5).
//
// Kept (T14, verified 272->181us): loads for rows r+2,r+3 ISSUED into
// registers right after the barrier, 2 rows of conv math run, then
// registers are COMMITTED to LDS. 2 rows/barrier, 4-row LDS ring.
// ring phase r%11 compile-time (pair period 22 == 0 mod 11).
//
// Round-2 lesson: __launch_bounds__(256,4) (128-VGPR cap) forced the ring
// into scratch. Cap at 256 VGPRs instead.

#define IH 512
#define IW 512
#define NCH 96            // 32*3 depthwise channels
#define TW 256            // tile width == blockDim.x
#define TH 34             // output rows per block
#define SSTR 272          // LDS row stride (266 used)
#define TYB 16            // ceil(512/34) block-rows
#define C1f (0.01f * 0.01f)
#define C2f (0.03f * 0.03f)

struct Weights { float w[11]; };

__global__ __launch_bounds__(256, 2) void ssim_kernel(
    const float* __restrict__ img1, const float* __restrict__ img2,
    float* __restrict__ partial, Weights wt)
{
    __shared__ float sA[4][SSTR];   // 4-row ring, buffer = row & 3
    __shared__ float sB[4][SSTR];
    __shared__ float wave_sums[4];

    const int tid = threadIdx.x;
    const int bx  = blockIdx.x;
    const int tx  = bx & 1;          // 2 col tiles
    const int ty  = (bx >> 1) & 15;  // 16 row tiles
    const int ch  = bx >> 5;         // 96 channels

    const int col0     = tx * TW;
    const int row_out0 = ty * TH;
    const int row0     = row_out0 - 5;       // staging row r -> global row row0+r
    const size_t choff = (size_t)ch * IH * IW;

    // column halo indices (fixed per thread)
    const int  gc0   = col0 - 5 + tid;
    const bool colv0 = ((unsigned)gc0 < (unsigned)IW);
    const int  gc1   = gc0 + TW;                   // staged by tid < 10
    const bool colv1 = ((unsigned)gc1 < (unsigned)IW);
    const bool halo  = (tid < 10);

    // two register staging slots (fixed names -> no runtime reg indexing)
    float pa0, pb0, pa1, pb1;        // slot P: even row of the pair
    float qa0, qb0, qa1, qb1;        // slot Q: odd row of the pair

    auto issue = [&](int r, float& a0, float& b0, float& a1, float& b1) {
        const int gr = row0 + r;                   // wave-uniform
        const bool rowv = ((unsigned)gr < (unsigned)IH);
        const long rowoff = (long)choff + (long)gr * IW;
        a0 = 0.f; b0 = 0.f; a1 = 0.f; b1 = 0.f;
        if (rowv & colv0) {
            a0 = img1[rowoff + gc0];
            b0 = img2[rowoff + gc0];
        }
        if (rowv & colv1 & halo) {
            a1 = img1[rowoff + gc1];
            b1 = img2[rowoff + gc1];
        }
    };
    // commit: raw stores, identical to the proven round-3 kernel
    auto commit = [&](int r, float a0, float b0, float a1, float b1) {
        const int p = r & 3;
        sA[p][tid] = a0;
        sB[p][tid] = b0;
        if (halo) {
            sA[p][tid + TW] = a1;
            sB[p][tid + TW] = b1;
        }
    };

    // accumulator ring: slot s holds output row o with o % 11 == s.
    // acc0=E[x], acc1=E[y], acc2=E[xy], acc3=E[x^2+y^2]
    // Zero-init only to avoid reading junk in the (discarded) warm-up emits.
    float acc0[11], acc1[11], acc2[11], acc3[11];
    #pragma unroll
    for (int s = 0; s < 11; ++s)
        acc0[s] = acc1[s] = acc2[s] = acc3[s] = 0.f;

    float tsum = 0.f;

    // prologue: rows 0,1 staged (one-time full-latency wait)
    issue(0, pa0, pb0, pa1, pb1);
    issue(1, qa0, qb0, qa1, qb1);
    commit(0, pa0, pb0, pa1, pb1);
    commit(1, qa0, qb0, qa1, qb1);

    for (int g = 0; g < 2; ++g) {
        #pragma unroll
        for (int jj = 0; jj < 11; ++jj) {
            const int rp = g * 22 + jj * 2;   // this pair computes rows rp, rp+1
            __syncthreads();                  // prev commits visible; prev reads done

            const bool more = (rp + 2) < 44;  // wave-uniform
            if (more) {
                issue(rp + 2, pa0, pb0, pa1, pb1);
                issue(rp + 3, qa0, qb0, qa1, qb1);
            }

            #pragma unroll
            for (int e = 0; e < 2; ++e) {
                const int r  = rp + e;
                const int ph = (2 * jj + e) % 11;   // == r % 11, compile-time
                const int p  = r & 3;               // LDS ring buffer (runtime ok)

                // ---- horizontal 11-tap conv straight from LDS ----
                const float* __restrict__ rowA = &sA[p][tid];
                const float* __restrict__ rowB = &sB[p][tid];
                float hx = 0.f, hy = 0.f, hxy = 0.f, hss = 0.f;
                #pragma unroll
                for (int k = 0; k < 11; ++k) {
                    const float a  = rowA[k];
                    const float b  = rowB[k];
                    const float wk = wt.w[k];
                    const float ta = wk * a;
                    const float tb = wk * b;
                    hx  += ta;
                    hy  += tb;
                    hxy += ta * b;
                    hss += ta * a;
                    hss += tb * b;
                }

                // ---- vertical conv: scatter into ring, weight idx (ph-s) mod 11.
                //      wi==0 is the first tap of the slot's window -> assign. ----
                #pragma unroll
                for (int s = 0; s < 11; ++s) {
                    const int wi = (ph - s + 11) % 11;   // compile-time
                    const float wk = wt.w[wi];
                    if (wi == 0) {
                        acc0[s] = wk * hx;
                        acc1[s] = wk * hy;
                        acc2[s] = wk * hxy;
                        acc3[s] = wk * hss;
                    } else {
                        acc0[s] += wk * hx;
                        acc1[s] += wk * hy;
                        acc2[s] += wk * hxy;
                        acc3[s] += wk * hss;
                    }
                }

                // ---- emit output row o = r-10 (slot (ph+1)%11) ----
                const int se = (ph + 1) % 11;           // compile-time
                const float mu1 = acc0[se], mu2 = acc1[se];
                const float m12 = acc2[se], mss = acc3[se];

                const float mu1s = mu1 * mu1;
                const float mu2s = mu2 * mu2;
                const float mu12 = mu1 * mu2;
                const float msum = mu1s + mu2s;
                const float num = (2.f * mu12 + C1f) * (2.f * (m12 - mu12) + C2f);
                const float den = (msum + C1f) * ((mss - msum) + C2f);

                // fast reciprocal: v_rcp (~1 ulp) + 1 Newton step
                float rc = __builtin_amdgcn_rcpf(den);
                rc = rc * fmaf(-den, rc, 2.0f);

                const int o = r - 10;
                const bool valid = (o >= 0) && (row_out0 + o < IH);
                tsum += valid ? (num * rc) : 0.f;
            }

            // ---- commit the prefetched pair: vmcnt wait covered by the
            //      conv math above. Loads never cross the barrier. ----
            if (more) {
                commit(rp + 2, pa0, pb0, pa1, pb1);
                commit(rp + 3, qa0, qb0, qa1, qb1);
            }
        }
    }

    // ---- block reduction ----
    #pragma unroll
    for (int off = 32; off > 0; off >>= 1)
        tsum += __shfl_down(tsum, off);
    if ((tid & 63) == 0) wave_sums[tid >> 6] = tsum;
    __syncthreads();
    if (tid == 0) {
        partial[blockIdx.x] =
            wave_sums[0] + wave_sums[1] + wave_sums[2] + wave_sums[3];
    }
}

__global__ __launch_bounds__(256) void reduce_kernel(
    const float* __restrict__ partial, int n, float* __restrict__ out,
    double inv_count)
{
    __shared__ double wave_sums[4];
    const int tid = threadIdx.x;
    double s = 0.0;
    for (int i = tid; i < n; i += 256) s += (double)partial[i];
    #pragma unroll
    for (int off = 32; off > 0; off >>= 1)
        s += __shfl_down(s, off);
    if ((tid & 63) == 0) wave_sums[tid >> 6] = s;
    __syncthreads();
    if (tid == 0) {
        out[0] = (float)((wave_sums[0] + wave_sums[1] +
                          wave_sums[2] + wave_sums[3]) * inv_count);
    }
}

extern "C" void kernel_launch(void* const* d_in, const int* in_sizes, int n_in,
                              void* d_out, int out_size, void* d_ws, size_t ws_size,
                              hipStream_t stream)
{
    const float* img1 = (const float*)d_in[0];
    const float* img2 = (const float*)d_in[1];
    float* out = (float*)d_out;
    float* partial = (float*)d_ws;   // 3072 floats = 12 KB scratch

    // Gaussian window (ws=11, sigma=1.5) in fp32, matching the reference
    Weights wt;
    {
        float s = 0.f;
        for (int i = 0; i < 11; ++i) {
            const float d = (float)(i - 5);
            wt.w[i] = expf(-(d * d) / 4.5f);
            s += wt.w[i];
        }
        for (int i = 0; i < 11; ++i) wt.w[i] /= s;
    }

    const int nblocks = NCH * TYB * 2;   // 3072

    ssim_kernel<<<nblocks, 256, 0, stream>>>(img1, img2, partial, wt);

    const double inv_count = 1.0 / ((double)NCH * IH * IW);
    reduce_kernel<<<1, 256, 0, stream>>>(partial, nblocks, out, inv_count);
}

// Round 6
// 593.477 us; speedup vs baseline: 1.9736x; 1.9736x over previous
//
#include <hip/hip_runtime.h>
#include <math.h>

// SSIM via fully separable pipeline, software-pipelined staging, TALL TILES.
// img1,img2: [32,3,512,512] fp32 -> scalar mean.
//
// Round-8: structural halo amortization. The proven round-3 kernel (181us,
// 84 VGPR, 84% VALUBusy) staged 44 rows to emit 34 (29% halo overhead).
// This version: TH=128 -> 138 staged rows per 128 outputs (7.8% overhead),
// 1.20x fewer total row computations. Grid 768 blocks (96ch x 4ty x 2tx).
// Inner 11-pair body is BYTE-IDENTICAL to round 3 (5-quantity h-conv,
// +=/* spelling, IEEE divide, acc ring, staging lambdas); outer group loop
// runs 6x with "#pragma unroll 1" (one body copy, same code footprint as
// round 3) + a 3-pair epilogue (rows 132..137; 132 == 0 mod 11 keeps every
// ring phase compile-time).
//
// SPILL BAN LIST (rounds 4-7 evidence): __builtin_amdgcn_rcpf + Newton
// (present in every 128-VGPR/GB-scratch round, absent in every clean one),
// 4-plane u/v LDS staging, hss accumulator merge (untested alone). The
// IEEE divide's serial chain appears to act as a scheduling serializer
// that keeps register pressure under the cliff. Do not "optimize" it.
//
// Kept (T14, verified 272->181us): loads for rows r+2,r+3 ISSUED into
// registers right after the barrier, 2 rows of conv math run, then
// registers are COMMITTED to LDS. 2 rows/barrier, 4-row LDS ring.
//
// Round-2 lesson: __launch_bounds__(256,4) (128-VGPR cap) forced the ring
// into scratch. Cap at 256 VGPRs instead.

#define IH 512
#define IW 512
#define NCH 96            // 32*3 depthwise channels
#define TW 256            // tile width == blockDim.x
#define TH 128            // output rows per block (138 staged)
#define NROWS 138         // TH + 10
#define SSTR 272          // LDS row stride (266 used)
#define TYB 4             // 512/128 row tiles
#define C1f (0.01f * 0.01f)
#define C2f (0.03f * 0.03f)

struct Weights { float w[11]; };

__global__ __launch_bounds__(256, 2) void ssim_kernel(
    const float* __restrict__ img1, const float* __restrict__ img2,
    float* __restrict__ partial, Weights wt)
{
    __shared__ float sA[4][SSTR];   // 4-row ring, buffer = row & 3
    __shared__ float sB[4][SSTR];
    __shared__ float wave_sums[4];

    const int tid = threadIdx.x;
    const int bx  = blockIdx.x;
    const int tx  = bx & 1;          // 2 col tiles
    const int ty  = (bx >> 1) & 3;   // 4 row tiles
    const int ch  = bx >> 3;         // 96 channels

    const int col0     = tx * TW;
    const int row_out0 = ty * TH;
    const int row0     = row_out0 - 5;       // staging row r -> global row row0+r
    const size_t choff = (size_t)ch * IH * IW;

    // column halo indices (fixed per thread)
    const int  gc0   = col0 - 5 + tid;
    const bool colv0 = ((unsigned)gc0 < (unsigned)IW);
    const int  gc1   = gc0 + TW;                   // staged by tid < 10
    const bool colv1 = ((unsigned)gc1 < (unsigned)IW);
    const bool halo  = (tid < 10);

    // two register staging slots (fixed names -> no runtime reg indexing)
    float pa0, pb0, pa1, pb1;        // slot P: even row of the pair
    float qa0, qb0, qa1, qb1;        // slot Q: odd row of the pair

    auto issue = [&](int r, float& a0, float& b0, float& a1, float& b1) {
        const int gr = row0 + r;                   // wave-uniform
        const bool rowv = ((unsigned)gr < (unsigned)IH);
        const long rowoff = (long)choff + (long)gr * IW;
        a0 = 0.f; b0 = 0.f; a1 = 0.f; b1 = 0.f;
        if (rowv & colv0) {
            a0 = img1[rowoff + gc0];
            b0 = img2[rowoff + gc0];
        }
        if (rowv & colv1 & halo) {
            a1 = img1[rowoff + gc1];
            b1 = img2[rowoff + gc1];
        }
    };
    auto commit = [&](int r, float a0, float b0, float a1, float b1) {
        const int p = r & 3;
        sA[p][tid] = a0;
        sB[p][tid] = b0;
        if (halo) {
            sA[p][tid + TW] = a1;
            sB[p][tid + TW] = b1;
        }
    };

    // accumulator ring: slot s holds output row o with o % 11 == s.
    // Zero-init only to avoid reading junk in the (discarded) warm-up emits.
    float acc0[11], acc1[11], acc2[11], acc3[11], acc4[11];
    #pragma unroll
    for (int s = 0; s < 11; ++s)
        acc0[s] = acc1[s] = acc2[s] = acc3[s] = acc4[s] = 0.f;

    float tsum = 0.f;

    // prologue: rows 0,1 staged (one-time full-latency wait)
    issue(0, pa0, pb0, pa1, pb1);
    issue(1, qa0, qb0, qa1, qb1);
    commit(0, pa0, pb0, pa1, pb1);
    commit(1, qa0, qb0, qa1, qb1);

    #pragma unroll 1
    for (int g = 0; g < 6; ++g) {
        const int gbase = g * 22;     // pair period 22 == 0 mod 11
        #pragma unroll
        for (int jj = 0; jj < 11; ++jj) {
            const int rp = gbase + jj * 2;    // this pair computes rows rp, rp+1
            __syncthreads();                  // prev commits visible; prev reads done

            const bool more = (rp + 2) < NROWS;  // wave-uniform
            if (more) {
                issue(rp + 2, pa0, pb0, pa1, pb1);
                issue(rp + 3, qa0, qb0, qa1, qb1);
            }

            #pragma unroll
            for (int e = 0; e < 2; ++e) {
                const int r  = rp + e;
                const int ph = (2 * jj + e) % 11;   // == r % 11, compile-time
                const int p  = r & 3;               // LDS ring buffer (runtime ok)

                // ---- horizontal 11-tap conv straight from LDS ----
                const float* __restrict__ rowA = &sA[p][tid];
                const float* __restrict__ rowB = &sB[p][tid];
                float hx = 0.f, hy = 0.f, hxx = 0.f, hyy = 0.f, hxy = 0.f;
                #pragma unroll
                for (int k = 0; k < 11; ++k) {
                    const float a  = rowA[k];
                    const float b  = rowB[k];
                    const float wk = wt.w[k];
                    const float ta = wk * a;
                    const float tb = wk * b;
                    hx  += ta;
                    hy  += tb;
                    hxx += ta * a;
                    hyy += tb * b;
                    hxy += ta * b;
                }

                // ---- vertical conv: scatter into ring, weight idx (ph-s) mod 11.
                //      wi==0 is the first tap of the slot's window -> assign. ----
                #pragma unroll
                for (int s = 0; s < 11; ++s) {
                    const int wi = (ph - s + 11) % 11;   // compile-time
                    const float wk = wt.w[wi];
                    if (wi == 0) {
                        acc0[s] = wk * hx;
                        acc1[s] = wk * hy;
                        acc2[s] = wk * hxx;
                        acc3[s] = wk * hyy;
                        acc4[s] = wk * hxy;
                    } else {
                        acc0[s] += wk * hx;
                        acc1[s] += wk * hy;
                        acc2[s] += wk * hxx;
                        acc3[s] += wk * hyy;
                        acc4[s] += wk * hxy;
                    }
                }

                // ---- emit output row o = r-10 (slot (ph+1)%11) ----
                const int se = (ph + 1) % 11;           // compile-time
                const float mu1 = acc0[se], mu2 = acc1[se];
                const float m11 = acc2[se], m22 = acc3[se], m12 = acc4[se];

                const float mu1s = mu1 * mu1;
                const float mu2s = mu2 * mu2;
                const float mu12 = mu1 * mu2;
                const float num = (2.f * mu12 + C1f) * (2.f * (m12 - mu12) + C2f);
                const float den = (mu1s + mu2s + C1f) *
                                  ((m11 - mu1s) + (m22 - mu2s) + C2f);
                const int o = r - 10;
                const bool valid = (o >= 0) && (row_out0 + o < IH);
                tsum += valid ? (num / den) : 0.f;
            }

            // ---- commit the prefetched pair: vmcnt wait covered by the
            //      conv math above. Loads never cross the barrier. ----
            if (more) {
                commit(rp + 2, pa0, pb0, pa1, pb1);
                commit(rp + 3, qa0, qb0, qa1, qb1);
            }
        }
    }

    // ---- epilogue: 3 pairs, rows 132..137 (132 == 0 mod 11) ----
    #pragma unroll
    for (int jj = 0; jj < 3; ++jj) {
        const int rp = 132 + jj * 2;
        __syncthreads();

        const bool more = (rp + 2) < NROWS;
        if (more) {
            issue(rp + 2, pa0, pb0, pa1, pb1);
            issue(rp + 3, qa0, qb0, qa1, qb1);
        }

        #pragma unroll
        for (int e = 0; e < 2; ++e) {
            const int r  = rp + e;
            const int ph = (2 * jj + e) % 11;   // == r % 11, compile-time
            const int p  = r & 3;

            const float* __restrict__ rowA = &sA[p][tid];
            const float* __restrict__ rowB = &sB[p][tid];
            float hx = 0.f, hy = 0.f, hxx = 0.f, hyy = 0.f, hxy = 0.f;
            #pragma unroll
            for (int k = 0; k < 11; ++k) {
                const float a  = rowA[k];
                const float b  = rowB[k];
                const float wk = wt.w[k];
                const float ta = wk * a;
                const float tb = wk * b;
                hx  += ta;
                hy  += tb;
                hxx += ta * a;
                hyy += tb * b;
                hxy += ta * b;
            }

            #pragma unroll
            for (int s = 0; s < 11; ++s) {
                const int wi = (ph - s + 11) % 11;
                const float wk = wt.w[wi];
                if (wi == 0) {
                    acc0[s] = wk * hx;
                    acc1[s] = wk * hy;
                    acc2[s] = wk * hxx;
                    acc3[s] = wk * hyy;
                    acc4[s] = wk * hxy;
                } else {
                    acc0[s] += wk * hx;
                    acc1[s] += wk * hy;
                    acc2[s] += wk * hxx;
                    acc3[s] += wk * hyy;
                    acc4[s] += wk * hxy;
                }
            }

            const int se = (ph + 1) % 11;
            const float mu1 = acc0[se], mu2 = acc1[se];
            const float m11 = acc2[se], m22 = acc3[se], m12 = acc4[se];

            const float mu1s = mu1 * mu1;
            const float mu2s = mu2 * mu2;
            const float mu12 = mu1 * mu2;
            const float num = (2.f * mu12 + C1f) * (2.f * (m12 - mu12) + C2f);
            const float den = (mu1s + mu2s + C1f) *
                              ((m11 - mu1s) + (m22 - mu2s) + C2f);
            const int o = r - 10;
            const bool valid = (o >= 0) && (row_out0 + o < IH);
            tsum += valid ? (num / den) : 0.f;
        }

        if (more) {
            commit(rp + 2, pa0, pb0, pa1, pb1);
            commit(rp + 3, qa0, qb0, qa1, qb1);
        }
    }

    // ---- block reduction ----
    #pragma unroll
    for (int off = 32; off > 0; off >>= 1)
        tsum += __shfl_down(tsum, off);
    if ((tid & 63) == 0) wave_sums[tid >> 6] = tsum;
    __syncthreads();
    if (tid == 0) {
        partial[blockIdx.x] =
            wave_sums[0] + wave_sums[1] + wave_sums[2] + wave_sums[3];
    }
}

__global__ __launch_bounds__(256) void reduce_kernel(
    const float* __restrict__ partial, int n, float* __restrict__ out,
    double inv_count)
{
    __shared__ double wave_sums[4];
    const int tid = threadIdx.x;
    double s = 0.0;
    for (int i = tid; i < n; i += 256) s += (double)partial[i];
    #pragma unroll
    for (int off = 32; off > 0; off >>= 1)
        s += __shfl_down(s, off);
    if ((tid & 63) == 0) wave_sums[tid >> 6] = s;
    __syncthreads();
    if (tid == 0) {
        out[0] = (float)((wave_sums[0] + wave_sums[1] +
                          wave_sums[2] + wave_sums[3]) * inv_count);
    }
}

extern "C" void kernel_launch(void* const* d_in, const int* in_sizes, int n_in,
                              void* d_out, int out_size, void* d_ws, size_t ws_size,
                              hipStream_t stream)
{
    const float* img1 = (const float*)d_in[0];
    const float* img2 = (const float*)d_in[1];
    float* out = (float*)d_out;
    float* partial = (float*)d_ws;   // 768 floats = 3 KB scratch

    // Gaussian window (ws=11, sigma=1.5) in fp32, matching the reference
    Weights wt;
    {
        float s = 0.f;
        for (int i = 0; i < 11; ++i) {
            const float d = (float)(i - 5);
            wt.w[i] = expf(-(d * d) / 4.5f);
            s += wt.w[i];
        }
        for (int i = 0; i < 11; ++i) wt.w[i] /= s;
    }

    const int nblocks = NCH * TYB * 2;   // 768

    ssim_kernel<<<nblocks, 256, 0, stream>>>(img1, img2, partial, wt);

    const double inv_count = 1.0 / ((double)NCH * IH * IW);
    reduce_kernel<<<1, 256, 0, stream>>>(partial, nblocks, out, inv_count);
}

// Round 7
// 337.297 us; speedup vs baseline: 3.4725x; 1.7595x over previous
//
#include <hip/hip_runtime.h>
#include <math.h>

// SSIM via fully separable pipeline, software-pipelined staging version.
// img1,img2: [32,3,512,512] fp32 -> scalar mean.
//
// Round-9: exact round-3 scaffold (proven clean twice: 84 VGPR, 181us, 84%
// VALUBusy) + ONE strictly-shrinking edit: the sigma terms are merged at the
// RING stage (emit only needs conv(x^2)+conv(y^2) as one quantity), so the
// v-conv ring is 4 quantities (44 fma/row, 44 ring regs) instead of 5
// (55/55). The h-conv keeps R1's independent hxx/hyy chains (byte-identical
// proven codegen); hsum = hxx+hyy costs 1 add per row-body.
//
// SPILL POST-MORTEM (rounds 4-8): every spilled round (VGPR pinned at 128,
// GB-scale scratch, 18x slowdowns) made row index r / LDS ring index p
// RUNTIME somewhere (explicit "#pragma unroll 1" outer loop, or the
// compiler declining to unroll an enlarged g-body) -> 22 hoisted LDS
// address registers + conditionally-live staging -> pressure past the
// ~128-VGPR cliff -> allocator dumps the acc ring to scratch. Every clean
// round has the fully-unrolled g<2 loop where r, p, and the 'more'
// predicate are compile-time constants and LDS reads are immediate-offset.
// DO NOT restructure the outer loop; DO NOT let r/p become runtime.
// (rcpf was exonerated by round 8: it spilled with the IEEE divide.)
//
// Kept (T14, verified 272->181us): loads for rows r+2,r+3 ISSUED into
// registers right after the barrier, 2 rows of conv math run, then
// registers are COMMITTED to LDS. 2 rows/barrier, 4-row LDS ring.
// ring phase r%11 compile-time (pair period 22 == 0 mod 11).
//
// Round-2 lesson: __launch_bounds__(256,4) (128-VGPR cap) forced the ring
// into scratch. Cap at 256 VGPRs instead.

#define IH 512
#define IW 512
#define NCH 96            // 32*3 depthwise channels
#define TW 256            // tile width == blockDim.x
#define TH 34             // output rows per block
#define SSTR 272          // LDS row stride (266 used)
#define TYB 16            // ceil(512/34) block-rows
#define C1f (0.01f * 0.01f)
#define C2f (0.03f * 0.03f)

struct Weights { float w[11]; };

__global__ __launch_bounds__(256, 2) void ssim_kernel(
    const float* __restrict__ img1, const float* __restrict__ img2,
    float* __restrict__ partial, Weights wt)
{
    __shared__ float sA[4][SSTR];   // 4-row ring, buffer = row & 3
    __shared__ float sB[4][SSTR];
    __shared__ float wave_sums[4];

    const int tid = threadIdx.x;
    const int bx  = blockIdx.x;
    const int tx  = bx & 1;          // 2 col tiles
    const int ty  = (bx >> 1) & 15;  // 16 row tiles
    const int ch  = bx >> 5;         // 96 channels

    const int col0     = tx * TW;
    const int row_out0 = ty * TH;
    const int row0     = row_out0 - 5;       // staging row r -> global row row0+r
    const size_t choff = (size_t)ch * IH * IW;

    // column halo indices (fixed per thread)
    const int  gc0   = col0 - 5 + tid;
    const bool colv0 = ((unsigned)gc0 < (unsigned)IW);
    const int  gc1   = gc0 + TW;                   // staged by tid < 10
    const bool colv1 = ((unsigned)gc1 < (unsigned)IW);
    const bool halo  = (tid < 10);

    // two register staging slots (fixed names -> no runtime reg indexing)
    float pa0, pb0, pa1, pb1;        // slot P: even row of the pair
    float qa0, qb0, qa1, qb1;        // slot Q: odd row of the pair

    auto issue = [&](int r, float& a0, float& b0, float& a1, float& b1) {
        const int gr = row0 + r;                   // wave-uniform
        const bool rowv = ((unsigned)gr < (unsigned)IH);
        const long rowoff = (long)choff + (long)gr * IW;
        a0 = 0.f; b0 = 0.f; a1 = 0.f; b1 = 0.f;
        if (rowv & colv0) {
            a0 = img1[rowoff + gc0];
            b0 = img2[rowoff + gc0];
        }
        if (rowv & colv1 & halo) {
            a1 = img1[rowoff + gc1];
            b1 = img2[rowoff + gc1];
        }
    };
    // commit: raw stores, identical to the proven round-3 kernel
    auto commit = [&](int r, float a0, float b0, float a1, float b1) {
        const int p = r & 3;
        sA[p][tid] = a0;
        sB[p][tid] = b0;
        if (halo) {
            sA[p][tid + TW] = a1;
            sB[p][tid + TW] = b1;
        }
    };

    // accumulator ring: slot s holds output row o with o % 11 == s.
    // acc0=E[x], acc1=E[y], acc2=E[xy], acc3=E[x^2]+E[y^2]
    // Zero-init only to avoid reading junk in the (discarded) warm-up emits.
    float acc0[11], acc1[11], acc2[11], acc3[11];
    #pragma unroll
    for (int s = 0; s < 11; ++s)
        acc0[s] = acc1[s] = acc2[s] = acc3[s] = 0.f;

    float tsum = 0.f;

    // prologue: rows 0,1 staged (one-time full-latency wait)
    issue(0, pa0, pb0, pa1, pb1);
    issue(1, qa0, qb0, qa1, qb1);
    commit(0, pa0, pb0, pa1, pb1);
    commit(1, qa0, qb0, qa1, qb1);

    for (int g = 0; g < 2; ++g) {
        #pragma unroll
        for (int jj = 0; jj < 11; ++jj) {
            const int rp = g * 22 + jj * 2;   // this pair computes rows rp, rp+1
            __syncthreads();                  // prev commits visible; prev reads done

            const bool more = (rp + 2) < 44;  // wave-uniform
            if (more) {
                issue(rp + 2, pa0, pb0, pa1, pb1);
                issue(rp + 3, qa0, qb0, qa1, qb1);
            }

            #pragma unroll
            for (int e = 0; e < 2; ++e) {
                const int r  = rp + e;
                const int ph = (2 * jj + e) % 11;   // == r % 11, compile-time
                const int p  = r & 3;               // LDS ring buffer (compile-time here)

                // ---- horizontal 11-tap conv straight from LDS ----
                // (byte-identical to the proven round-3 kernel)
                const float* __restrict__ rowA = &sA[p][tid];
                const float* __restrict__ rowB = &sB[p][tid];
                float hx = 0.f, hy = 0.f, hxx = 0.f, hyy = 0.f, hxy = 0.f;
                #pragma unroll
                for (int k = 0; k < 11; ++k) {
                    const float a  = rowA[k];
                    const float b  = rowB[k];
                    const float wk = wt.w[k];
                    const float ta = wk * a;
                    const float tb = wk * b;
                    hx  += ta;
                    hy  += tb;
                    hxx += ta * a;
                    hyy += tb * b;
                    hxy += ta * b;
                }
                const float hsum = hxx + hyy;   // sigma merge: 1 add here,
                                                // saves 11 fma in the ring

                // ---- vertical conv: scatter into ring, weight idx (ph-s) mod 11.
                //      wi==0 is the first tap of the slot's window -> assign. ----
                #pragma unroll
                for (int s = 0; s < 11; ++s) {
                    const int wi = (ph - s + 11) % 11;   // compile-time
                    const float wk = wt.w[wi];
                    if (wi == 0) {
                        acc0[s] = wk * hx;
                        acc1[s] = wk * hy;
                        acc2[s] = wk * hxy;
                        acc3[s] = wk * hsum;
                    } else {
                        acc0[s] += wk * hx;
                        acc1[s] += wk * hy;
                        acc2[s] += wk * hxy;
                        acc3[s] += wk * hsum;
                    }
                }

                // ---- emit output row o = r-10 (slot (ph+1)%11) ----
                const int se = (ph + 1) % 11;           // compile-time
                const float mu1 = acc0[se], mu2 = acc1[se];
                const float m12 = acc2[se], mss = acc3[se];

                const float mu1s = mu1 * mu1;
                const float mu2s = mu2 * mu2;
                const float mu12 = mu1 * mu2;
                const float num = (2.f * mu12 + C1f) * (2.f * (m12 - mu12) + C2f);
                const float den = (mu1s + mu2s + C1f) *
                                  (((mss - mu1s) - mu2s) + C2f);
                const int o = r - 10;
                const bool valid = (o >= 0) && (row_out0 + o < IH);
                tsum += valid ? (num / den) : 0.f;
            }

            // ---- commit the prefetched pair: vmcnt wait covered by the
            //      conv math above. Loads never cross the barrier. ----
            if (more) {
                commit(rp + 2, pa0, pb0, pa1, pb1);
                commit(rp + 3, qa0, qb0, qa1, qb1);
            }
        }
    }

    // ---- block reduction ----
    #pragma unroll
    for (int off = 32; off > 0; off >>= 1)
        tsum += __shfl_down(tsum, off);
    if ((tid & 63) == 0) wave_sums[tid >> 6] = tsum;
    __syncthreads();
    if (tid == 0) {
        partial[blockIdx.x] =
            wave_sums[0] + wave_sums[1] + wave_sums[2] + wave_sums[3];
    }
}

__global__ __launch_bounds__(256) void reduce_kernel(
    const float* __restrict__ partial, int n, float* __restrict__ out,
    double inv_count)
{
    __shared__ double wave_sums[4];
    const int tid = threadIdx.x;
    double s = 0.0;
    for (int i = tid; i < n; i += 256) s += (double)partial[i];
    #pragma unroll
    for (int off = 32; off > 0; off >>= 1)
        s += __shfl_down(s, off);
    if ((tid & 63) == 0) wave_sums[tid >> 6] = s;
    __syncthreads();
    if (tid == 0) {
        out[0] = (float)((wave_sums[0] + wave_sums[1] +
                          wave_sums[2] + wave_sums[3]) * inv_count);
    }
}

extern "C" void kernel_launch(void* const* d_in, const int* in_sizes, int n_in,
                              void* d_out, int out_size, void* d_ws, size_t ws_size,
                              hipStream_t stream)
{
    const float* img1 = (const float*)d_in[0];
    const float* img2 = (const float*)d_in[1];
    float* out = (float*)d_out;
    float* partial = (float*)d_ws;   // 3072 floats = 12 KB scratch

    // Gaussian window (ws=11, sigma=1.5) in fp32, matching the reference
    Weights wt;
    {
        float s = 0.f;
        for (int i = 0; i < 11; ++i) {
            const float d = (float)(i - 5);
            wt.w[i] = expf(-(d * d) / 4.5f);
            s += wt.w[i];
        }
        for (int i = 0; i < 11; ++i) wt.w[i] /= s;
    }

    const int nblocks = NCH * TYB * 2;   // 3072

    ssim_kernel<<<nblocks, 256, 0, stream>>>(img1, img2, partial, wt);

    const double inv_count = 1.0 / ((double)NCH * IH * IW);
    reduce_kernel<<<1, 256, 0, stream>>>(partial, nblocks, out, inv_count);
}